// Round 1
// baseline (1079.432 us; speedup 1.0000x reference)
//
#include <hip/hip_runtime.h>

typedef unsigned short u16;
typedef unsigned int   u32;
typedef __attribute__((ext_vector_type(4))) float floatx4;
typedef __attribute__((ext_vector_type(8))) short shortx8;
typedef __attribute__((ext_vector_type(8))) u16   ushortx8;

#define B_   2
#define S_   2048
#define DIM_ 4096
#define NH_  32
#define NKV_ 8
#define HD_  128
#define MTOT (B_*S_)            // 4096 rows
#define NQKV (NH_*HD_ + 2*NKV_*HD_)  // 6144
#define QSCALE 0.08838834764831845f  // 1/sqrt(128)

__device__ inline u16 f2bf(float f) {
  u32 x = __builtin_bit_cast(u32, f);
  x += 0x7fffu + ((x >> 16) & 1u);   // RNE
  return (u16)(x >> 16);
}
__device__ inline float bf2f(u16 u) {
  u32 x = ((u32)u) << 16;
  return __builtin_bit_cast(float, x);
}
__device__ inline shortx8 ldfrag(const u16* p) {
  return __builtin_bit_cast(shortx8, *(const uint4*)p);
}

// ---------------- fp32 -> bf16 cast (x) ----------------
__global__ __launch_bounds__(256) void cvt_f32_bf16(const float* __restrict__ src,
                                                    u16* __restrict__ dst) {
  int i = blockIdx.x * 256 + threadIdx.x;          // 8 elems / thread
  const float4* s4 = (const float4*)src;
  float4 a = s4[2*i], c = s4[2*i+1];
  ushortx8 o;
  o[0]=f2bf(a.x); o[1]=f2bf(a.y); o[2]=f2bf(a.z); o[3]=f2bf(a.w);
  o[4]=f2bf(c.x); o[5]=f2bf(c.y); o[6]=f2bf(c.z); o[7]=f2bf(c.w);
  *(ushortx8*)(dst + (size_t)i*8) = o;
}

// ---------------- weight transpose + cast: w (K,N) fp32 -> wt (N,K) bf16 ----------------
__global__ __launch_bounds__(256) void transpose_cvt(const float* __restrict__ w,
                                                     u16* __restrict__ wt, int K, int N) {
  __shared__ float tile[32][33];
  int n0 = blockIdx.x * 32, k0 = blockIdx.y * 32;
  int tx = threadIdx.x & 31, ty = threadIdx.x >> 5;
#pragma unroll
  for (int i = 0; i < 4; i++) {
    int r = ty*4 + i;
    tile[r][tx] = w[(size_t)(k0 + r)*N + n0 + tx];
  }
  __syncthreads();
#pragma unroll
  for (int i = 0; i < 4; i++) {
    int n = ty*4 + i;
    wt[(size_t)(n0 + n)*K + k0 + tx] = f2bf(tile[tx][n]);
  }
}

// ---------------- GEMM: C(M,N) = A(M,K) @ Bt(N,K)^T, bf16 in, fp32 acc ----------------
// 128x128 tile, BK=64, 4 waves each 64x64 via 4x4 16x16x32 MFMAs.
template<int OUT_BF16>
__global__ __launch_bounds__(256) void gemm_bt(const u16* __restrict__ A,
                                               const u16* __restrict__ Bt,
                                               void* __restrict__ Cv,
                                               int M, int N, int K) {
  __shared__ u16 As[128*72];   // +8 pad: bank-balanced b128 access
  __shared__ u16 Bs[128*72];
  const int tid = threadIdx.x;
  const int w = tid >> 6, l = tid & 63, quad = l >> 4, c16 = l & 15;
  const int bm = blockIdx.y * 128, bn = blockIdx.x * 128;
  const int wm = (w & 1) * 64, wn = (w >> 1) * 64;
  floatx4 acc[4][4];
#pragma unroll
  for (int mi = 0; mi < 4; mi++)
#pragma unroll
    for (int ni = 0; ni < 4; ni++) acc[mi][ni] = floatx4{0.f,0.f,0.f,0.f};

  for (int k0 = 0; k0 < K; k0 += 64) {
    __syncthreads();
#pragma unroll
    for (int rep = 0; rep < 4; rep++) {          // 1024 16B-chunks each for A,B
      int c = rep*256 + tid;
      int r = c >> 3, cc = c & 7;                // 8 chunks per 64-elem row
      uint4 va = *(const uint4*)(A  + (size_t)(bm + r)*K + k0 + cc*8);
      uint4 vb = *(const uint4*)(Bt + (size_t)(bn + r)*K + k0 + cc*8);
      *(uint4*)(As + r*72 + cc*8) = va;
      *(uint4*)(Bs + r*72 + cc*8) = vb;
    }
    __syncthreads();
#pragma unroll
    for (int ks = 0; ks < 2; ks++) {
      shortx8 af[4], bfr[4];
#pragma unroll
      for (int mi = 0; mi < 4; mi++)
        af[mi] = ldfrag(As + (wm + mi*16 + c16)*72 + ks*32 + quad*8);
#pragma unroll
      for (int ni = 0; ni < 4; ni++)
        bfr[ni] = ldfrag(Bs + (wn + ni*16 + c16)*72 + ks*32 + quad*8);
#pragma unroll
      for (int mi = 0; mi < 4; mi++)
#pragma unroll
        for (int ni = 0; ni < 4; ni++)
          acc[mi][ni] = __builtin_amdgcn_mfma_f32_16x16x32_bf16(af[mi], bfr[ni], acc[mi][ni], 0, 0, 0);
    }
  }
  // epilogue: C/D layout col=lane&15, row=quad*4+reg
#pragma unroll
  for (int mi = 0; mi < 4; mi++)
#pragma unroll
    for (int i = 0; i < 4; i++) {
      int row = bm + wm + mi*16 + quad*4 + i;
#pragma unroll
      for (int ni = 0; ni < 4; ni++) {
        int col = bn + wn + ni*16 + c16;
        float v = acc[mi][ni][i];
        if (OUT_BF16) ((u16*)Cv)[(size_t)row*N + col] = f2bf(v);
        else          ((float*)Cv)[(size_t)row*N + col] = v;
      }
    }
}

// ---------------- RoPE on q,k parts of qkv_pre; Q pre-scaled by 1/sqrt(HD) ----------------
__global__ __launch_bounds__(256) void rope_kernel(const u16* __restrict__ qkv,
                                                   const float* __restrict__ fc,
                                                   const float* __restrict__ fs,
                                                   u16* __restrict__ q_r,
                                                   u16* __restrict__ k_r) {
  u32 idx  = blockIdx.x * 256 + threadIdx.x;     // MTOT*40*64 pairs
  u32 t    = idx & 63;
  u32 rest = idx >> 6;
  u32 m    = rest / 40u;
  u32 hh   = rest - m*40u;
  u32 s    = m & (S_ - 1);
  float c  = fc[s*64 + t], sn = fs[s*64 + t];
  u32 src; u16* dst; u32 dstoff; float scale;
  if (hh < (u32)NH_) {
    src = m*NQKV + hh*HD_ + 2*t;  dst = q_r;  dstoff = m*(NH_*HD_) + hh*HD_ + 2*t;  scale = QSCALE;
  } else {
    u32 hk = hh - NH_;
    src = m*NQKV + NH_*HD_ + hk*HD_ + 2*t;  dst = k_r;  dstoff = m*(NKV_*HD_) + hk*HD_ + 2*t;  scale = 1.f;
  }
  u32 pair = *(const u32*)(qkv + src);
  float xr = bf2f((u16)(pair & 0xffffu));
  float xi = bf2f((u16)(pair >> 16));
  float orr = (xr*c - xi*sn) * scale;
  float oii = (xr*sn + xi*c) * scale;
  u32 outp = (u32)f2bf(orr) | ((u32)f2bf(oii) << 16);
  *(u32*)(dst + dstoff) = outp;
}

// ---------------- V transpose: qkv_pre v-part (m, hk, d) -> vt (b, hk, d, s) ----------------
__global__ __launch_bounds__(256) void v_transpose(const u16* __restrict__ qkv,
                                                   u16* __restrict__ vt) {
  __shared__ u16 tile[32][33];
  int bh = blockIdx.y; int b = bh >> 3, hk = bh & 7;
  int ts = (blockIdx.x & 63) * 32;   // s tile
  int td = (blockIdx.x >> 6) * 32;   // d tile
  int tx = threadIdx.x & 31, ty = threadIdx.x >> 5;
#pragma unroll
  for (int i = 0; i < 4; i++) {
    int r = ty*4 + i;
    tile[r][tx] = qkv[(size_t)(b*S_ + ts + r)*NQKV + (NH_*HD_ + NKV_*HD_) + hk*HD_ + td + tx];
  }
  __syncthreads();
#pragma unroll
  for (int i = 0; i < 4; i++) {
    int d = ty*4 + i;
    vt[((size_t)bh*HD_ + td + d)*S_ + ts + tx] = tile[tx][d];
  }
}

// ---------------- Flash attention: 64-query tile per block, online softmax ----------------
__global__ __launch_bounds__(256) void attn_kernel(const u16* __restrict__ Q,
                                                   const u16* __restrict__ Kr,
                                                   const u16* __restrict__ Vt,
                                                   u16* __restrict__ Out) {
  __shared__ u16 Qs[64*136];
  __shared__ u16 Ks[64*136];
  __shared__ u16 Vts[128*72];
  __shared__ u16 Ps[4*16*72];
  const int tid = threadIdx.x;
  const int w = tid >> 6, l = tid & 63, quad = l >> 4, c16 = l & 15;
  const int qt = blockIdx.x, h = blockIdx.y, b = blockIdx.z;
  const int hk = h >> 2;                 // GQA: 4 query heads per kv head

  // stage Q tile (64 x 128)
#pragma unroll
  for (int rep = 0; rep < 4; rep++) {
    int c = rep*256 + tid;
    int r = c >> 4, cc = c & 15;
    uint4 v = *(const uint4*)(Q + (size_t)(b*S_ + qt*64 + r)*(NH_*HD_) + h*HD_ + cc*8);
    *(uint4*)(Qs + r*136 + cc*8) = v;
  }
  __syncthreads();
  shortx8 aq[4];
#pragma unroll
  for (int kk = 0; kk < 4; kk++)
    aq[kk] = ldfrag(Qs + (w*16 + c16)*136 + kk*32 + quad*8);

  floatx4 o[8];
#pragma unroll
  for (int f = 0; f < 8; f++) o[f] = floatx4{0.f,0.f,0.f,0.f};
  float mrow[4] = {-1e30f,-1e30f,-1e30f,-1e30f};
  float lrow[4] = {0.f,0.f,0.f,0.f};
  u16* pw = Ps + w*16*72;

  for (int kt = 0; kt < S_/64; kt++) {
    __syncthreads();
#pragma unroll
    for (int rep = 0; rep < 4; rep++) {
      int c = rep*256 + tid;
      int r = c >> 4, cc = c & 15;
      uint4 v = *(const uint4*)(Kr + (size_t)(b*S_ + kt*64 + r)*(NKV_*HD_) + hk*HD_ + cc*8);
      *(uint4*)(Ks + r*136 + cc*8) = v;
      int d = c >> 3, cc2 = c & 7;
      uint4 v2 = *(const uint4*)(Vt + ((size_t)(b*NKV_ + hk)*HD_ + d)*S_ + kt*64 + cc2*8);
      *(uint4*)(Vts + d*72 + cc2*8) = v2;
    }
    __syncthreads();

    // S = Q Kt^T  (scores pre-scaled via Q)
    floatx4 sc[4];
#pragma unroll
    for (int nt = 0; nt < 4; nt++) sc[nt] = floatx4{0.f,0.f,0.f,0.f};
#pragma unroll
    for (int kk = 0; kk < 4; kk++)
#pragma unroll
      for (int nt = 0; nt < 4; nt++) {
        shortx8 bk = ldfrag(Ks + (nt*16 + c16)*136 + kk*32 + quad*8);
        sc[nt] = __builtin_amdgcn_mfma_f32_16x16x32_bf16(aq[kk], bk, sc[nt], 0, 0, 0);
      }

    // online softmax: row r = quad*4+i, reduce across the 16 lanes of this quad
    float alpha[4];
#pragma unroll
    for (int i = 0; i < 4; i++) {
      float mx = fmaxf(fmaxf(sc[0][i], sc[1][i]), fmaxf(sc[2][i], sc[3][i]));
      mx = fmaxf(mx, __shfl_xor(mx, 1));
      mx = fmaxf(mx, __shfl_xor(mx, 2));
      mx = fmaxf(mx, __shfl_xor(mx, 4));
      mx = fmaxf(mx, __shfl_xor(mx, 8));
      float mn = fmaxf(mrow[i], mx);
      float al = __expf(mrow[i] - mn);
      mrow[i] = mn;
      float rs = 0.f;
#pragma unroll
      for (int nt = 0; nt < 4; nt++) { float p = __expf(sc[nt][i] - mn); sc[nt][i] = p; rs += p; }
      rs += __shfl_xor(rs, 1);
      rs += __shfl_xor(rs, 2);
      rs += __shfl_xor(rs, 4);
      rs += __shfl_xor(rs, 8);
      lrow[i] = lrow[i]*al + rs;
      alpha[i] = al;
    }
#pragma unroll
    for (int f = 0; f < 8; f++)
#pragma unroll
      for (int i = 0; i < 4; i++) o[f][i] *= alpha[i];

    // P: C-layout regs -> LDS -> A-layout frags (per-wave private region)
#pragma unroll
    for (int nt = 0; nt < 4; nt++)
#pragma unroll
      for (int i = 0; i < 4; i++)
        pw[(quad*4 + i)*72 + nt*16 + c16] = f2bf(sc[nt][i]);
    asm volatile("s_waitcnt lgkmcnt(0)" ::: "memory");

    // O += P @ V
#pragma unroll
    for (int kk2 = 0; kk2 < 2; kk2++) {
      shortx8 pf = ldfrag(pw + c16*72 + kk2*32 + quad*8);
#pragma unroll
      for (int f = 0; f < 8; f++) {
        shortx8 vf = ldfrag(Vts + (f*16 + c16)*72 + kk2*32 + quad*8);
        o[f] = __builtin_amdgcn_mfma_f32_16x16x32_bf16(pf, vf, o[f], 0, 0, 0);
      }
    }
  }

  // normalize + store bf16
#pragma unroll
  for (int i = 0; i < 4; i++) {
    int srow = qt*64 + w*16 + quad*4 + i;
    float inv = 1.f / lrow[i];
    size_t base = (size_t)(b*S_ + srow)*(NH_*HD_) + h*HD_;
#pragma unroll
    for (int f = 0; f < 8; f++)
      Out[base + f*16 + c16] = f2bf(o[f][i] * inv);
  }
}

extern "C" void kernel_launch(void* const* d_in, const int* in_sizes, int n_in,
                              void* d_out, int out_size, void* d_ws, size_t ws_size,
                              hipStream_t stream) {
  (void)in_sizes; (void)n_in; (void)out_size; (void)ws_size;
  const float* x  = (const float*)d_in[0];
  // d_in[1] = start_pos (unused; reference ignores it)
  const float* fc = (const float*)d_in[2];
  const float* fs = (const float*)d_in[3];
  const float* wq = (const float*)d_in[4];
  const float* wk = (const float*)d_in[5];
  const float* wv = (const float*)d_in[6];
  const float* wo = (const float*)d_in[7];
  float* out = (float*)d_out;

  // workspace layout (160 MB total), with lifetime-based reuse:
  char* ws = (char*)d_ws;
  u16* xb    = (u16*)(ws);                    // x bf16 (33.5MB); reused as attn_out after QKV
  u16* wallt = (u16*)(ws + 33554432ull);      // [wq|wk|wv]^T bf16, 6144x4096 (50.3MB)
  u16* q_r   = (u16*)(ws + 33554432ull);      // overlays wallt after QKV GEMM (33.5MB)
  u16* k_r   = (u16*)(ws + 67108864ull);      // (8.4MB)
  u16* vt    = (u16*)(ws + 75497472ull);      // (8.4MB)
  u16* wot   = (u16*)(ws + 83886080ull);      // wo^T bf16 (33.5MB)
  u16* qkvp  = (u16*)(ws + 117440512ull);     // qkv_pre bf16, 4096x6144 (50.3MB); end 160MB

  cvt_f32_bf16<<<8192, 256, 0, stream>>>(x, xb);
  transpose_cvt<<<dim3(128,128), 256, 0, stream>>>(wq, wallt, 4096, 4096);
  transpose_cvt<<<dim3(32,128),  256, 0, stream>>>(wk, wallt + (size_t)4096*4096, 4096, 1024);
  transpose_cvt<<<dim3(32,128),  256, 0, stream>>>(wv, wallt + (size_t)5120*4096, 4096, 1024);
  transpose_cvt<<<dim3(128,128), 256, 0, stream>>>(wo, wot, 4096, 4096);

  gemm_bt<1><<<dim3(48,32), 256, 0, stream>>>(xb, wallt, qkvp, MTOT, NQKV, DIM_);

  rope_kernel<<<40960, 256, 0, stream>>>(qkvp, fc, fs, q_r, k_r);
  v_transpose<<<dim3(256,16), 256, 0, stream>>>(qkvp, vt);

  attn_kernel<<<dim3(32,32,2), 256, 0, stream>>>(q_r, k_r, vt, xb);

  gemm_bt<0><<<dim3(32,32), 256, 0, stream>>>(xb, wot, out, MTOT, DIM_, 4096);
}

// Round 2
// 1077.397 us; speedup vs baseline: 1.0019x; 1.0019x over previous
//
#include <hip/hip_runtime.h>

typedef unsigned short u16;
typedef unsigned int   u32;
typedef __attribute__((ext_vector_type(4))) float floatx4;
typedef __attribute__((ext_vector_type(8))) short shortx8;
typedef __attribute__((ext_vector_type(8))) u16   ushortx8;

#define B_   2
#define S_   2048
#define DIM_ 4096
#define NH_  32
#define NKV_ 8
#define HD_  128
#define MTOT (B_*S_)            // 4096 rows
#define NQKV (NH_*HD_ + 2*NKV_*HD_)  // 6144
// Q pre-scale: 1/sqrt(128) * log2(e)  -> scores in log2 domain, softmax uses exp2
#define QSCALE 0.12753785735803168f
#define KSCALE 1.0f

typedef __attribute__((address_space(3))) u32 lds_u32;
typedef const __attribute__((address_space(1))) u32 gbl_u32;

__device__ inline u16 f2bf(float f) {                 // native RNE cvt (v_cvt_pk_bf16_f32)
  __bf16 h = (__bf16)f;
  return __builtin_bit_cast(u16, h);
}
__device__ inline float bf2f(u16 u) {
  u32 x = ((u32)u) << 16;
  return __builtin_bit_cast(float, x);
}
__device__ inline shortx8 ldfrag(const u16* p) {
  return __builtin_bit_cast(shortx8, *(const uint4*)p);
}

// ---------------- fp32 -> bf16 cast (x) ----------------
__global__ __launch_bounds__(256) void cvt_f32_bf16(const float* __restrict__ src,
                                                    u16* __restrict__ dst) {
  int i = blockIdx.x * 256 + threadIdx.x;          // 8 elems / thread
  const float4* s4 = (const float4*)src;
  float4 a = s4[2*i], c = s4[2*i+1];
  ushortx8 o;
  o[0]=f2bf(a.x); o[1]=f2bf(a.y); o[2]=f2bf(a.z); o[3]=f2bf(a.w);
  o[4]=f2bf(c.x); o[5]=f2bf(c.y); o[6]=f2bf(c.z); o[7]=f2bf(c.w);
  *(ushortx8*)(dst + (size_t)i*8) = o;
}

// ---------------- weight transpose + cast: w (K,N) fp32 -> wt (N,K) bf16 ----------------
__global__ __launch_bounds__(256) void transpose_cvt(const float* __restrict__ w,
                                                     u16* __restrict__ wt, int K, int N) {
  __shared__ float tile[32][33];
  int n0 = blockIdx.x * 32, k0 = blockIdx.y * 32;
  int tx = threadIdx.x & 31, ty = threadIdx.x >> 5;
#pragma unroll
  for (int i = 0; i < 4; i++) {
    int r = ty*4 + i;
    tile[r][tx] = w[(size_t)(k0 + r)*N + n0 + tx];
  }
  __syncthreads();
#pragma unroll
  for (int i = 0; i < 4; i++) {
    int n = ty*4 + i;
    wt[(size_t)(n0 + n)*K + k0 + tx] = f2bf(tile[tx][n]);
  }
}

// ---------------- GEMM: C(M,N) = A(M,K) @ Bt(N,K)^T, bf16 in, fp32 acc ----------------
// m97 structure: 128x128 tile, BK=64, global_load_lds width-16 staging (unpadded LDS),
// 4 waves each 64x64 via 4x4 16x16x32 MFMAs.
template<int OUT_BF16>
__global__ __launch_bounds__(256) void gemm_bt(const u16* __restrict__ A,
                                               const u16* __restrict__ Bt,
                                               void* __restrict__ Cv,
                                               int M, int N, int K) {
  __shared__ u16 As[128*64];   // unpadded: required by global_load_lds lane-order dest
  __shared__ u16 Bs[128*64];
  const int tid = threadIdx.x;
  const int w = tid >> 6, l = tid & 63, quad = l >> 4, c16 = l & 15;
  const int bm = blockIdx.y * 128, bn = blockIdx.x * 128;
  const int wm = (w & 1) * 64, wn = (w >> 1) * 64;
  const int drow = l >> 3;         // 0..7  (8 rows per 1KB DMA instr)
  const int dcol = (l & 7) * 8;    // u16 col offset (16B chunks)
  floatx4 acc[4][4];
#pragma unroll
  for (int mi = 0; mi < 4; mi++)
#pragma unroll
    for (int ni = 0; ni < 4; ni++) acc[mi][ni] = floatx4{0.f,0.f,0.f,0.f};

  for (int k0 = 0; k0 < K; k0 += 64) {
    __syncthreads();
    // DMA stage: wave w covers rows [w*32, w*32+32) of both tiles, 4 instrs of 1KB each.
#pragma unroll
    for (int j = 0; j < 4; j++) {
      int row = w*32 + j*8 + drow;
      __builtin_amdgcn_global_load_lds(
          (gbl_u32*)(A + (size_t)(bm + row)*K + k0 + dcol),
          (lds_u32*)(As + (w*32 + j*8)*64), 16, 0, 0);
      __builtin_amdgcn_global_load_lds(
          (gbl_u32*)(Bt + (size_t)(bn + row)*K + k0 + dcol),
          (lds_u32*)(Bs + (w*32 + j*8)*64), 16, 0, 0);
    }
    __syncthreads();
#pragma unroll
    for (int ks = 0; ks < 2; ks++) {
      shortx8 af[4], bfr[4];
#pragma unroll
      for (int mi = 0; mi < 4; mi++)
        af[mi] = ldfrag(As + (wm + mi*16 + c16)*64 + ks*32 + quad*8);
#pragma unroll
      for (int ni = 0; ni < 4; ni++)
        bfr[ni] = ldfrag(Bs + (wn + ni*16 + c16)*64 + ks*32 + quad*8);
#pragma unroll
      for (int mi = 0; mi < 4; mi++)
#pragma unroll
        for (int ni = 0; ni < 4; ni++)
          acc[mi][ni] = __builtin_amdgcn_mfma_f32_16x16x32_bf16(af[mi], bfr[ni], acc[mi][ni], 0, 0, 0);
    }
  }
  // epilogue: C/D layout col=lane&15, row=quad*4+reg
#pragma unroll
  for (int mi = 0; mi < 4; mi++)
#pragma unroll
    for (int i = 0; i < 4; i++) {
      int row = bm + wm + mi*16 + quad*4 + i;
#pragma unroll
      for (int ni = 0; ni < 4; ni++) {
        int col = bn + wn + ni*16 + c16;
        float v = acc[mi][ni][i];
        if (OUT_BF16) ((u16*)Cv)[(size_t)row*N + col] = f2bf(v);
        else          ((float*)Cv)[(size_t)row*N + col] = v;
      }
    }
}

// ---------------- RoPE on q,k parts of qkv_pre; Q pre-scaled by log2e/sqrt(HD) ----------------
__global__ __launch_bounds__(256) void rope_kernel(const u16* __restrict__ qkv,
                                                   const float* __restrict__ fc,
                                                   const float* __restrict__ fs,
                                                   u16* __restrict__ q_r,
                                                   u16* __restrict__ k_r) {
  u32 idx  = blockIdx.x * 256 + threadIdx.x;     // MTOT*40*64 pairs
  u32 t    = idx & 63;
  u32 rest = idx >> 6;
  u32 m    = rest / 40u;
  u32 hh   = rest - m*40u;
  u32 s    = m & (S_ - 1);
  float c  = fc[s*64 + t], sn = fs[s*64 + t];
  u32 src; u16* dst; u32 dstoff; float scale;
  if (hh < (u32)NH_) {
    src = m*NQKV + hh*HD_ + 2*t;  dst = q_r;  dstoff = m*(NH_*HD_) + hh*HD_ + 2*t;  scale = QSCALE;
  } else {
    u32 hk = hh - NH_;
    src = m*NQKV + NH_*HD_ + hk*HD_ + 2*t;  dst = k_r;  dstoff = m*(NKV_*HD_) + hk*HD_ + 2*t;  scale = KSCALE;
  }
  u32 pair = *(const u32*)(qkv + src);
  float xr = bf2f((u16)(pair & 0xffffu));
  float xi = bf2f((u16)(pair >> 16));
  float orr = (xr*c - xi*sn) * scale;
  float oii = (xr*sn + xi*c) * scale;
  u32 outp = (u32)f2bf(orr) | ((u32)f2bf(oii) << 16);
  *(u32*)(dst + dstoff) = outp;
}

// ---------------- V transpose: qkv_pre v-part (m, hk, d) -> vt (b, hk, d, s) ----------------
__global__ __launch_bounds__(256) void v_transpose(const u16* __restrict__ qkv,
                                                   u16* __restrict__ vt) {
  __shared__ u16 tile[32][33];
  int bh = blockIdx.y; int b = bh >> 3, hk = bh & 7;
  int ts = (blockIdx.x & 63) * 32;   // s tile
  int td = (blockIdx.x >> 6) * 32;   // d tile
  int tx = threadIdx.x & 31, ty = threadIdx.x >> 5;
#pragma unroll
  for (int i = 0; i < 4; i++) {
    int r = ty*4 + i;
    tile[r][tx] = qkv[(size_t)(b*S_ + ts + r)*NQKV + (NH_*HD_ + NKV_*HD_) + hk*HD_ + td + tx];
  }
  __syncthreads();
#pragma unroll
  for (int i = 0; i < 4; i++) {
    int d = ty*4 + i;
    vt[((size_t)bh*HD_ + td + d)*S_ + ts + tx] = tile[tx][d];
  }
}

// ---------------- Flash attention: 64-query tile per block, online softmax (log2 domain) ----------------
__global__ __launch_bounds__(256) void attn_kernel(const u16* __restrict__ Q,
                                                   const u16* __restrict__ Kr,
                                                   const u16* __restrict__ Vt,
                                                   u16* __restrict__ Out) {
  __shared__ u16 Qs[64*136];         // Q staging; reused as P after fragment load
  __shared__ u16 Ks[64*136];
  __shared__ u16 Vts[128*72];
  const int tid = threadIdx.x;
  const int w = tid >> 6, l = tid & 63, quad = l >> 4, c16 = l & 15;
  const int qt = blockIdx.x, h = blockIdx.y, b = blockIdx.z;
  const int hk = h >> 2;                 // GQA: 4 query heads per kv head

  // stage Q tile (64 x 128)
#pragma unroll
  for (int rep = 0; rep < 4; rep++) {
    int c = rep*256 + tid;
    int r = c >> 4, cc = c & 15;
    uint4 v = *(const uint4*)(Q + (size_t)(b*S_ + qt*64 + r)*(NH_*HD_) + h*HD_ + cc*8);
    *(uint4*)(Qs + r*136 + cc*8) = v;
  }
  __syncthreads();
  shortx8 aq[4];
#pragma unroll
  for (int kk = 0; kk < 4; kk++)
    aq[kk] = ldfrag(Qs + (w*16 + c16)*136 + kk*32 + quad*8);

  floatx4 o[8];
#pragma unroll
  for (int f = 0; f < 8; f++) o[f] = floatx4{0.f,0.f,0.f,0.f};
  float mrow[4] = {-1e30f,-1e30f,-1e30f,-1e30f};
  float lrow[4] = {0.f,0.f,0.f,0.f};
  u16* pw = Qs + w*16*72;     // P overlay on dead Qs region (per-wave private)

  for (int kt = 0; kt < S_/64; kt++) {
    __syncthreads();
#pragma unroll
    for (int rep = 0; rep < 4; rep++) {
      int c = rep*256 + tid;
      int r = c >> 4, cc = c & 15;
      uint4 v = *(const uint4*)(Kr + (size_t)(b*S_ + kt*64 + r)*(NKV_*HD_) + hk*HD_ + cc*8);
      *(uint4*)(Ks + r*136 + cc*8) = v;
      int d = c >> 3, cc2 = c & 7;
      uint4 v2 = *(const uint4*)(Vt + ((size_t)(b*NKV_ + hk)*HD_ + d)*S_ + kt*64 + cc2*8);
      *(uint4*)(Vts + d*72 + cc2*8) = v2;
    }
    __syncthreads();

    // S = Q Kt^T  (log2-domain: Q pre-scaled by log2e/sqrt(HD))
    floatx4 sc[4];
#pragma unroll
    for (int nt = 0; nt < 4; nt++) sc[nt] = floatx4{0.f,0.f,0.f,0.f};
#pragma unroll
    for (int kk = 0; kk < 4; kk++)
#pragma unroll
      for (int nt = 0; nt < 4; nt++) {
        shortx8 bk = ldfrag(Ks + (nt*16 + c16)*136 + kk*32 + quad*8);
        sc[nt] = __builtin_amdgcn_mfma_f32_16x16x32_bf16(aq[kk], bk, sc[nt], 0, 0, 0);
      }

    // online softmax: row r = quad*4+i, reduce across the 16 lanes of this quad
    float alpha[4];
#pragma unroll
    for (int i = 0; i < 4; i++) {
      float mx = fmaxf(fmaxf(sc[0][i], sc[1][i]), fmaxf(sc[2][i], sc[3][i]));
      mx = fmaxf(mx, __shfl_xor(mx, 1));
      mx = fmaxf(mx, __shfl_xor(mx, 2));
      mx = fmaxf(mx, __shfl_xor(mx, 4));
      mx = fmaxf(mx, __shfl_xor(mx, 8));
      float mn = fmaxf(mrow[i], mx);
      float al = __builtin_amdgcn_exp2f(mrow[i] - mn);
      mrow[i] = mn;
      float rs = 0.f;
#pragma unroll
      for (int nt = 0; nt < 4; nt++) {
        float p = __builtin_amdgcn_exp2f(sc[nt][i] - mn);
        sc[nt][i] = p; rs += p;
      }
      rs += __shfl_xor(rs, 1);
      rs += __shfl_xor(rs, 2);
      rs += __shfl_xor(rs, 4);
      rs += __shfl_xor(rs, 8);
      lrow[i] = lrow[i]*al + rs;
      alpha[i] = al;
    }
#pragma unroll
    for (int f = 0; f < 8; f++)
#pragma unroll
      for (int i = 0; i < 4; i++) o[f][i] *= alpha[i];

    // P: C-layout regs -> LDS -> A-layout frags (per-wave private region)
#pragma unroll
    for (int nt = 0; nt < 4; nt++)
#pragma unroll
      for (int i = 0; i < 4; i++)
        pw[(quad*4 + i)*72 + nt*16 + c16] = f2bf(sc[nt][i]);
    asm volatile("s_waitcnt lgkmcnt(0)" ::: "memory");

    // O += P @ V
#pragma unroll
    for (int kk2 = 0; kk2 < 2; kk2++) {
      shortx8 pf = ldfrag(pw + c16*72 + kk2*32 + quad*8);
#pragma unroll
      for (int f = 0; f < 8; f++) {
        shortx8 vf = ldfrag(Vts + (f*16 + c16)*72 + kk2*32 + quad*8);
        o[f] = __builtin_amdgcn_mfma_f32_16x16x32_bf16(pf, vf, o[f], 0, 0, 0);
      }
    }
  }

  // normalize + store bf16
#pragma unroll
  for (int i = 0; i < 4; i++) {
    int srow = qt*64 + w*16 + quad*4 + i;
    float inv = 1.f / lrow[i];
    size_t base = (size_t)(b*S_ + srow)*(NH_*HD_) + h*HD_;
#pragma unroll
    for (int f = 0; f < 8; f++)
      Out[base + f*16 + c16] = f2bf(o[f][i] * inv);
  }
}

extern "C" void kernel_launch(void* const* d_in, const int* in_sizes, int n_in,
                              void* d_out, int out_size, void* d_ws, size_t ws_size,
                              hipStream_t stream) {
  (void)in_sizes; (void)n_in; (void)out_size; (void)ws_size;
  const float* x  = (const float*)d_in[0];
  // d_in[1] = start_pos (unused; reference ignores it)
  const float* fc = (const float*)d_in[2];
  const float* fs = (const float*)d_in[3];
  const float* wq = (const float*)d_in[4];
  const float* wk = (const float*)d_in[5];
  const float* wv = (const float*)d_in[6];
  const float* wo = (const float*)d_in[7];
  float* out = (float*)d_out;

  // workspace layout (160 MB total), with lifetime-based reuse:
  char* ws = (char*)d_ws;
  u16* xb    = (u16*)(ws);                    // x bf16 (33.5MB); reused as attn_out after QKV
  u16* wallt = (u16*)(ws + 33554432ull);      // [wq|wk|wv]^T bf16, 6144x4096 (50.3MB)
  u16* q_r   = (u16*)(ws + 33554432ull);      // overlays wallt after QKV GEMM (33.5MB)
  u16* k_r   = (u16*)(ws + 67108864ull);      // (8.4MB)
  u16* vt    = (u16*)(ws + 75497472ull);      // (8.4MB)
  u16* wot   = (u16*)(ws + 83886080ull);      // wo^T bf16 (33.5MB)
  u16* qkvp  = (u16*)(ws + 117440512ull);     // qkv_pre bf16, 4096x6144 (50.3MB); end 160MB

  cvt_f32_bf16<<<8192, 256, 0, stream>>>(x, xb);
  transpose_cvt<<<dim3(128,128), 256, 0, stream>>>(wq, wallt, 4096, 4096);
  transpose_cvt<<<dim3(32,128),  256, 0, stream>>>(wk, wallt + (size_t)4096*4096, 4096, 1024);
  transpose_cvt<<<dim3(32,128),  256, 0, stream>>>(wv, wallt + (size_t)5120*4096, 4096, 1024);
  transpose_cvt<<<dim3(128,128), 256, 0, stream>>>(wo, wot, 4096, 4096);

  gemm_bt<1><<<dim3(48,32), 256, 0, stream>>>(xb, wallt, qkvp, MTOT, NQKV, DIM_);

  rope_kernel<<<40960, 256, 0, stream>>>(qkvp, fc, fs, q_r, k_r);
  v_transpose<<<dim3(256,16), 256, 0, stream>>>(qkvp, vt);

  attn_kernel<<<dim3(32,32,2), 256, 0, stream>>>(q_r, k_r, vt, xb);

  gemm_bt<0><<<dim3(32,32), 256, 0, stream>>>(xb, wot, out, MTOT, DIM_, 4096);
}

// Round 3
// 964.323 us; speedup vs baseline: 1.1194x; 1.1173x over previous
//
#include <hip/hip_runtime.h>

typedef unsigned short u16;
typedef unsigned int   u32;
typedef __attribute__((ext_vector_type(4))) float floatx4;
typedef __attribute__((ext_vector_type(8))) short shortx8;
typedef __attribute__((ext_vector_type(8))) u16   ushortx8;

#define B_   2
#define S_   2048
#define DIM_ 4096
#define NH_  32
#define NKV_ 8
#define HD_  128
#define MTOT (B_*S_)            // 4096 rows
#define NQKV (NH_*HD_ + 2*NKV_*HD_)  // 6144
// Q pre-scale: 1/sqrt(128) * log2(e)  -> scores in log2 domain, softmax uses exp2
#define QSCALE 0.12753785735803168f
#define KSCALE 1.0f

typedef __attribute__((address_space(3))) u32 lds_u32;
typedef const __attribute__((address_space(1))) u32 gbl_u32;

__device__ inline u16 f2bf(float f) {                 // native RNE cvt
  __bf16 h = (__bf16)f;
  return __builtin_bit_cast(u16, h);
}
__device__ inline float bf2f(u16 u) {
  u32 x = ((u32)u) << 16;
  return __builtin_bit_cast(float, x);
}
__device__ inline shortx8 ldfrag(const u16* p) {
  return __builtin_bit_cast(shortx8, *(const uint4*)p);
}

// ---------------- fp32 -> bf16 cast (x) ----------------
__global__ __launch_bounds__(256) void cvt_f32_bf16(const float* __restrict__ src,
                                                    u16* __restrict__ dst) {
  int i = blockIdx.x * 256 + threadIdx.x;          // 8 elems / thread
  const float4* s4 = (const float4*)src;
  float4 a = s4[2*i], c = s4[2*i+1];
  ushortx8 o;
  o[0]=f2bf(a.x); o[1]=f2bf(a.y); o[2]=f2bf(a.z); o[3]=f2bf(a.w);
  o[4]=f2bf(c.x); o[5]=f2bf(c.y); o[6]=f2bf(c.z); o[7]=f2bf(c.w);
  *(ushortx8*)(dst + (size_t)i*8) = o;
}

// ---------------- weight transpose + cast: w (K,N) fp32 -> wt (N,K) bf16 ----------------
__global__ __launch_bounds__(256) void transpose_cvt(const float* __restrict__ w,
                                                     u16* __restrict__ wt, int K, int N) {
  __shared__ float tile[32][33];
  int n0 = blockIdx.x * 32, k0 = blockIdx.y * 32;
  int tx = threadIdx.x & 31, ty = threadIdx.x >> 5;
#pragma unroll
  for (int i = 0; i < 4; i++) {
    int r = ty*4 + i;
    tile[r][tx] = w[(size_t)(k0 + r)*N + n0 + tx];
  }
  __syncthreads();
#pragma unroll
  for (int i = 0; i < 4; i++) {
    int n = ty*4 + i;
    wt[(size_t)(n0 + n)*K + k0 + tx] = f2bf(tile[tx][n]);
  }
}

// ---------------- GEMM: C(M,N) = A(M,K) @ Bt(N,K)^T, bf16 in, fp32 acc ----------------
// m97 structure + XOR-swizzled LDS: 128x128 tile, BK=64, global_load_lds width-16.
// Element (row, k) of a tile lives at LDS chunk ((k>>3) ^ (row&7)) within its row
// (chunk = 16B = 8 u16). DMA lane l fetches global chunk (l&7)^(l>>3) so the
// fixed lane->LDS slot mapping lands it at the swizzled position. Fragment
// ds_read_b128 then spreads a quad's 16 lanes across all 8 chunk slots ->
// 2 lanes/bank = conflict-free (m136: 2-way is free).
template<int OUT_BF16>
__global__ __launch_bounds__(256) void gemm_bt(const u16* __restrict__ A,
                                               const u16* __restrict__ Bt,
                                               void* __restrict__ Cv,
                                               int M, int N, int K) {
  __shared__ u16 As[128*64];
  __shared__ u16 Bs[128*64];
  const int tid = threadIdx.x;
  const int w = tid >> 6, l = tid & 63, quad = l >> 4, c16 = l & 15;
  const int bm = blockIdx.y * 128, bn = blockIdx.x * 128;
  const int wm = (w & 1) * 64, wn = (w >> 1) * 64;
  const int drow = l >> 3;                  // 0..7  (8 rows per 1KB DMA instr)
  const int gchunk = (l & 7) ^ drow;        // swizzled global chunk this lane fetches
  const int dcol = gchunk * 8;              // u16 col offset
  floatx4 acc[4][4];
#pragma unroll
  for (int mi = 0; mi < 4; mi++)
#pragma unroll
    for (int ni = 0; ni < 4; ni++) acc[mi][ni] = floatx4{0.f,0.f,0.f,0.f};

  for (int k0 = 0; k0 < K; k0 += 64) {
    __syncthreads();
    // DMA stage: wave w covers rows [w*32, w*32+32) of both tiles, 4 instrs of 1KB each.
#pragma unroll
    for (int j = 0; j < 4; j++) {
      int row = w*32 + j*8 + drow;          // rowbase&7 == 0, so row&7 == drow
      __builtin_amdgcn_global_load_lds(
          (gbl_u32*)(A + (size_t)(bm + row)*K + k0 + dcol),
          (lds_u32*)(As + (w*32 + j*8)*64), 16, 0, 0);
      __builtin_amdgcn_global_load_lds(
          (gbl_u32*)(Bt + (size_t)(bn + row)*K + k0 + dcol),
          (lds_u32*)(Bs + (w*32 + j*8)*64), 16, 0, 0);
    }
    __syncthreads();
#pragma unroll
    for (int ks = 0; ks < 2; ks++) {
      shortx8 af[4], bfr[4];
#pragma unroll
      for (int mi = 0; mi < 4; mi++) {
        int row = wm + mi*16 + c16;
        int ch  = (ks*4 + quad) ^ (row & 7);
        af[mi] = ldfrag(As + row*64 + ch*8);
      }
#pragma unroll
      for (int ni = 0; ni < 4; ni++) {
        int row = wn + ni*16 + c16;
        int ch  = (ks*4 + quad) ^ (row & 7);
        bfr[ni] = ldfrag(Bs + row*64 + ch*8);
      }
#pragma unroll
      for (int mi = 0; mi < 4; mi++)
#pragma unroll
        for (int ni = 0; ni < 4; ni++)
          acc[mi][ni] = __builtin_amdgcn_mfma_f32_16x16x32_bf16(af[mi], bfr[ni], acc[mi][ni], 0, 0, 0);
    }
  }
  // epilogue: C/D layout col=lane&15, row=quad*4+reg
#pragma unroll
  for (int mi = 0; mi < 4; mi++)
#pragma unroll
    for (int i = 0; i < 4; i++) {
      int row = bm + wm + mi*16 + quad*4 + i;
#pragma unroll
      for (int ni = 0; ni < 4; ni++) {
        int col = bn + wn + ni*16 + c16;
        float v = acc[mi][ni][i];
        if (OUT_BF16) ((u16*)Cv)[(size_t)row*N + col] = f2bf(v);
        else          ((float*)Cv)[(size_t)row*N + col] = v;
      }
    }
}

// ---------------- RoPE on q,k parts of qkv_pre; Q pre-scaled by log2e/sqrt(HD) ----------------
__global__ __launch_bounds__(256) void rope_kernel(const u16* __restrict__ qkv,
                                                   const float* __restrict__ fc,
                                                   const float* __restrict__ fs,
                                                   u16* __restrict__ q_r,
                                                   u16* __restrict__ k_r) {
  u32 idx  = blockIdx.x * 256 + threadIdx.x;     // MTOT*40*64 pairs
  u32 t    = idx & 63;
  u32 rest = idx >> 6;
  u32 m    = rest / 40u;
  u32 hh   = rest - m*40u;
  u32 s    = m & (S_ - 1);
  float c  = fc[s*64 + t], sn = fs[s*64 + t];
  u32 src; u16* dst; u32 dstoff; float scale;
  if (hh < (u32)NH_) {
    src = m*NQKV + hh*HD_ + 2*t;  dst = q_r;  dstoff = m*(NH_*HD_) + hh*HD_ + 2*t;  scale = QSCALE;
  } else {
    u32 hk = hh - NH_;
    src = m*NQKV + NH_*HD_ + hk*HD_ + 2*t;  dst = k_r;  dstoff = m*(NKV_*HD_) + hk*HD_ + 2*t;  scale = KSCALE;
  }
  u32 pair = *(const u32*)(qkv + src);
  float xr = bf2f((u16)(pair & 0xffffu));
  float xi = bf2f((u16)(pair >> 16));
  float orr = (xr*c - xi*sn) * scale;
  float oii = (xr*sn + xi*c) * scale;
  u32 outp = (u32)f2bf(orr) | ((u32)f2bf(oii) << 16);
  *(u32*)(dst + dstoff) = outp;
}

// ---------------- V transpose: qkv_pre v-part (m, hk, d) -> vt (b, hk, d, s) ----------------
__global__ __launch_bounds__(256) void v_transpose(const u16* __restrict__ qkv,
                                                   u16* __restrict__ vt) {
  __shared__ u16 tile[32][33];
  int bh = blockIdx.y; int b = bh >> 3, hk = bh & 7;
  int ts = (blockIdx.x & 63) * 32;   // s tile
  int td = (blockIdx.x >> 6) * 32;   // d tile
  int tx = threadIdx.x & 31, ty = threadIdx.x >> 5;
#pragma unroll
  for (int i = 0; i < 4; i++) {
    int r = ty*4 + i;
    tile[r][tx] = qkv[(size_t)(b*S_ + ts + r)*NQKV + (NH_*HD_ + NKV_*HD_) + hk*HD_ + td + tx];
  }
  __syncthreads();
#pragma unroll
  for (int i = 0; i < 4; i++) {
    int d = ty*4 + i;
    vt[((size_t)bh*HD_ + td + d)*S_ + ts + tx] = tile[tx][d];
  }
}

// ---------------- Flash attention: 64-query tile per block, online softmax (log2 domain) ----------------
__global__ __launch_bounds__(256) void attn_kernel(const u16* __restrict__ Q,
                                                   const u16* __restrict__ Kr,
                                                   const u16* __restrict__ Vt,
                                                   u16* __restrict__ Out) {
  __shared__ u16 Qs[64*136];         // Q staging; reused as P after fragment load
  __shared__ u16 Ks[64*136];
  __shared__ u16 Vts[128*72];
  const int tid = threadIdx.x;
  const int w = tid >> 6, l = tid & 63, quad = l >> 4, c16 = l & 15;
  const int qt = blockIdx.x, h = blockIdx.y, b = blockIdx.z;
  const int hk = h >> 2;                 // GQA: 4 query heads per kv head

  // stage Q tile (64 x 128)
#pragma unroll
  for (int rep = 0; rep < 4; rep++) {
    int c = rep*256 + tid;
    int r = c >> 4, cc = c & 15;
    uint4 v = *(const uint4*)(Q + (size_t)(b*S_ + qt*64 + r)*(NH_*HD_) + h*HD_ + cc*8);
    *(uint4*)(Qs + r*136 + cc*8) = v;
  }
  __syncthreads();
  shortx8 aq[4];
#pragma unroll
  for (int kk = 0; kk < 4; kk++)
    aq[kk] = ldfrag(Qs + (w*16 + c16)*136 + kk*32 + quad*8);

  floatx4 o[8];
#pragma unroll
  for (int f = 0; f < 8; f++) o[f] = floatx4{0.f,0.f,0.f,0.f};
  float mrow[4] = {-1e30f,-1e30f,-1e30f,-1e30f};
  float lrow[4] = {0.f,0.f,0.f,0.f};
  u16* pw = Qs + w*16*72;     // P overlay on dead Qs region (per-wave private)

  for (int kt = 0; kt < S_/64; kt++) {
    __syncthreads();
#pragma unroll
    for (int rep = 0; rep < 4; rep++) {
      int c = rep*256 + tid;
      int r = c >> 4, cc = c & 15;
      uint4 v = *(const uint4*)(Kr + (size_t)(b*S_ + kt*64 + r)*(NKV_*HD_) + hk*HD_ + cc*8);
      *(uint4*)(Ks + r*136 + cc*8) = v;
      int d = c >> 3, cc2 = c & 7;
      uint4 v2 = *(const uint4*)(Vt + ((size_t)(b*NKV_ + hk)*HD_ + d)*S_ + kt*64 + cc2*8);
      *(uint4*)(Vts + d*72 + cc2*8) = v2;
    }
    __syncthreads();

    // S = Q Kt^T  (log2-domain: Q pre-scaled by log2e/sqrt(HD))
    floatx4 sc[4];
#pragma unroll
    for (int nt = 0; nt < 4; nt++) sc[nt] = floatx4{0.f,0.f,0.f,0.f};
#pragma unroll
    for (int kk = 0; kk < 4; kk++)
#pragma unroll
      for (int nt = 0; nt < 4; nt++) {
        shortx8 bk = ldfrag(Ks + (nt*16 + c16)*136 + kk*32 + quad*8);
        sc[nt] = __builtin_amdgcn_mfma_f32_16x16x32_bf16(aq[kk], bk, sc[nt], 0, 0, 0);
      }

    // online softmax: row r = quad*4+i, reduce across the 16 lanes of this quad
    float alpha[4];
#pragma unroll
    for (int i = 0; i < 4; i++) {
      float mx = fmaxf(fmaxf(sc[0][i], sc[1][i]), fmaxf(sc[2][i], sc[3][i]));
      mx = fmaxf(mx, __shfl_xor(mx, 1));
      mx = fmaxf(mx, __shfl_xor(mx, 2));
      mx = fmaxf(mx, __shfl_xor(mx, 4));
      mx = fmaxf(mx, __shfl_xor(mx, 8));
      float mn = fmaxf(mrow[i], mx);
      float al = __builtin_amdgcn_exp2f(mrow[i] - mn);
      mrow[i] = mn;
      float rs = 0.f;
#pragma unroll
      for (int nt = 0; nt < 4; nt++) {
        float p = __builtin_amdgcn_exp2f(sc[nt][i] - mn);
        sc[nt][i] = p; rs += p;
      }
      rs += __shfl_xor(rs, 1);
      rs += __shfl_xor(rs, 2);
      rs += __shfl_xor(rs, 4);
      rs += __shfl_xor(rs, 8);
      lrow[i] = lrow[i]*al + rs;
      alpha[i] = al;
    }
#pragma unroll
    for (int f = 0; f < 8; f++)
#pragma unroll
      for (int i = 0; i < 4; i++) o[f][i] *= alpha[i];

    // P: C-layout regs -> LDS -> A-layout frags (per-wave private region)
#pragma unroll
    for (int nt = 0; nt < 4; nt++)
#pragma unroll
      for (int i = 0; i < 4; i++)
        pw[(quad*4 + i)*72 + nt*16 + c16] = f2bf(sc[nt][i]);
    asm volatile("s_waitcnt lgkmcnt(0)" ::: "memory");

    // O += P @ V
#pragma unroll
    for (int kk2 = 0; kk2 < 2; kk2++) {
      shortx8 pf = ldfrag(pw + c16*72 + kk2*32 + quad*8);
#pragma unroll
      for (int f = 0; f < 8; f++) {
        shortx8 vf = ldfrag(Vts + (f*16 + c16)*72 + kk2*32 + quad*8);
        o[f] = __builtin_amdgcn_mfma_f32_16x16x32_bf16(pf, vf, o[f], 0, 0, 0);
      }
    }
  }

  // normalize + store bf16
#pragma unroll
  for (int i = 0; i < 4; i++) {
    int srow = qt*64 + w*16 + quad*4 + i;
    float inv = 1.f / lrow[i];
    size_t base = (size_t)(b*S_ + srow)*(NH_*HD_) + h*HD_;
#pragma unroll
    for (int f = 0; f < 8; f++)
      Out[base + f*16 + c16] = f2bf(o[f][i] * inv);
  }
}

extern "C" void kernel_launch(void* const* d_in, const int* in_sizes, int n_in,
                              void* d_out, int out_size, void* d_ws, size_t ws_size,
                              hipStream_t stream) {
  (void)in_sizes; (void)n_in; (void)out_size; (void)ws_size;
  const float* x  = (const float*)d_in[0];
  // d_in[1] = start_pos (unused; reference ignores it)
  const float* fc = (const float*)d_in[2];
  const float* fs = (const float*)d_in[3];
  const float* wq = (const float*)d_in[4];
  const float* wk = (const float*)d_in[5];
  const float* wv = (const float*)d_in[6];
  const float* wo = (const float*)d_in[7];
  float* out = (float*)d_out;

  // workspace layout (160 MB total), with lifetime-based reuse:
  char* ws = (char*)d_ws;
  u16* xb    = (u16*)(ws);                    // x bf16 (33.5MB); reused as attn_out after QKV
  u16* wallt = (u16*)(ws + 33554432ull);      // [wq|wk|wv]^T bf16, 6144x4096 (50.3MB)
  u16* q_r   = (u16*)(ws + 33554432ull);      // overlays wallt after QKV GEMM (33.5MB)
  u16* k_r   = (u16*)(ws + 67108864ull);      // (8.4MB)
  u16* vt    = (u16*)(ws + 75497472ull);      // (8.4MB)
  u16* wot   = (u16*)(ws + 83886080ull);      // wo^T bf16 (33.5MB)
  u16* qkvp  = (u16*)(ws + 117440512ull);     // qkv_pre bf16, 4096x6144 (50.3MB); end 160MB

  cvt_f32_bf16<<<8192, 256, 0, stream>>>(x, xb);
  transpose_cvt<<<dim3(128,128), 256, 0, stream>>>(wq, wallt, 4096, 4096);
  transpose_cvt<<<dim3(32,128),  256, 0, stream>>>(wk, wallt + (size_t)4096*4096, 4096, 1024);
  transpose_cvt<<<dim3(32,128),  256, 0, stream>>>(wv, wallt + (size_t)5120*4096, 4096, 1024);
  transpose_cvt<<<dim3(128,128), 256, 0, stream>>>(wo, wot, 4096, 4096);

  gemm_bt<1><<<dim3(48,32), 256, 0, stream>>>(xb, wallt, qkvp, MTOT, NQKV, DIM_);

  rope_kernel<<<40960, 256, 0, stream>>>(qkvp, fc, fs, q_r, k_r);
  v_transpose<<<dim3(256,16), 256, 0, stream>>>(qkvp, vt);

  attn_kernel<<<dim3(32,32,2), 256, 0, stream>>>(q_r, k_r, vt, xb);

  gemm_bt<0><<<dim3(32,32), 256, 0, stream>>>(xb, wot, out, MTOT, DIM_, 4096);
}